// Round 18
// baseline (27.654 us; speedup 1.0000x reference)
//
#include <hip/hip_runtime.h>

#define NQ 11

// TWO waves per sample. Amplitude index i (wire w <-> bit (10-w) of i):
//   i = (b<<10) | (k<<7) | (comp<<6) | lane
//   wire 0      -> wave bit b      (LDS exchange, 1 barrier/layer, dbuf)
//   wires 1..3  -> k bits 2..0     (packed f32x2 register butterflies)
//   wire 4      -> comp            (within-f32x2 butterfly)
//   wires 5..10 -> lane bits 5..0  (cross-lane: shfl 32/16, DPP 8/4/2/1)
// CZ gates folded into the NEXT RY's coefficients (verified r2/r3/r5/r6/r9).
// Rationale (r17 counters): 2 waves/SIMD left VALU idle 68% (10+ stall
// cyc/instr). Splitting samples across 2 waves doubles TLP and halves
// per-wave work; DS pipe is idle in the current gate mix (DPP + 2 batched
// shfl gates), so the added exchange/barrier traffic can hide under VALU.

typedef float f32x2 __attribute__((ext_vector_type(2)));

__device__ __forceinline__ f32x2 b2(float s) { f32x2 r; r.x = s; r.y = s; return r; }
__device__ __forceinline__ f32x2 fma2(f32x2 a, f32x2 b, f32x2 c) {
    return __builtin_elementwise_fma(a, b, c);
}

template <int CTRL>
__device__ __forceinline__ float dpp_mov(float x) {
    const int xi = __builtin_bit_cast(int, x);
    return __builtin_bit_cast(float,
        __builtin_amdgcn_update_dpp(xi, xi, CTRL, 0xf, 0xf, false));
}
#define DPP_XOR1 0xB1   // quad_perm [1,0,3,2]
#define DPP_XOR2 0x4E   // quad_perm [2,3,0,1]
#define DPP_XOR3 0x1B   // quad_perm [3,2,1,0]
#define DPP_XOR7 0x141  // row_half_mirror
#define DPP_XOR8 0x128  // row_ror:8 (xor-8 within 16-lane row)

// Packed butterfly on k-bit KB over 8 regs; CZ sign: -1 iff (k0 & KSB).
#define RY_K_F8(KB, KSB, C, S)                                               \
    _Pragma("unroll")                                                        \
    for (int g = 0; g < 4; ++g) {                                            \
        const int k0 = ((g >> (KB)) << ((KB) + 1)) | (g & ((1 << (KB)) - 1));\
        const int k1 = k0 | (1 << (KB));                                     \
        const f32x2 a_ = v2[k0], bb_ = v2[k1];                               \
        const f32x2 Cv = b2(C), Sv = b2(S);                                  \
        if (k0 & (KSB)) {                                                    \
            v2[k0] = fma2(Cv, a_, Sv * bb_);                                 \
            v2[k1] = fma2(Sv, a_, -(Cv * bb_));                              \
        } else {                                                             \
            v2[k0] = fma2(Cv, a_, -(Sv * bb_));                              \
            v2[k1] = fma2(Sv, a_, Cv * bb_);                                 \
        }                                                                    \
    }

// DS shuffle gate, BATCHED (verified r9), 8-reg form.
#define RY_DS_B8(SHFL, CV, SV)                                               \
    {                                                                        \
        f32x2 pa_[8];                                                        \
        _Pragma("unroll")                                                    \
        for (int k = 0; k < 8; ++k) {                                        \
            pa_[k].x = SHFL(v2[k].x);                                        \
            pa_[k].y = SHFL(v2[k].y);                                        \
        }                                                                    \
        _Pragma("unroll")                                                    \
        for (int k = 0; k < 8; ++k)                                          \
            v2[k] = fma2(CV, v2[k], (SV) * pa_[k]);                          \
    }

// DPP lane gate (verified r5/r6), 8-reg form.
#define RY_DPP8(PGETX, CV, SV)                                               \
    _Pragma("unroll")                                                        \
    for (int k = 0; k < 8; ++k) {                                            \
        f32x2 pa_;                                                           \
        pa_.x = PGETX(v2[k].x);                                              \
        pa_.y = PGETX(v2[k].y);                                              \
        v2[k] = fma2(CV, v2[k], (SV) * pa_);                                 \
    }

__global__ __launch_bounds__(256, 4) void qru_kernel(
    const float* __restrict__ x,   // [2048, 16]
    const float* __restrict__ w,   // [11]
    float* __restrict__ out)       // [2048, 11]
{
    const int tid  = threadIdx.x;
    const int lane = tid & 63;
    const int wid  = tid >> 6;      // 0..3
    const int sloc = wid >> 1;      // sample within block
    const int b    = wid & 1;       // wave bit = wire 0
    const int n    = blockIdx.x * 2 + sloc;

    __shared__ f32x2 buf[2][4][8][64];  // [dbuf][wid][k][lane] = 32 KB
    __shared__ float qbuf[4][12];

    // ---- input angles + half-angle sin/cos ----
    const float4 xa = *(const float4*)(x + n * 16);
    const float4 xb = *(const float4*)(x + n * 16 + 4);
    const float4 xc = *(const float4*)(x + n * 16 + 8);
    const float xv[NQ] = {xa.x, xa.y, xa.z, xa.w, xb.x, xb.y, xb.z, xb.w,
                          xc.x, xc.y, xc.z};
    float ci[NQ], si[NQ];
#pragma unroll
    for (int q = 0; q < NQ; ++q) {
        const float h = xv[q] * 0.5f;
        si[q] = __sinf(h); ci[q] = __cosf(h);
    }
    float cw[NQ], sw[NQ];
#pragma unroll
    for (int q = 0; q < NQ; ++q) {
        const float h = w[q] * 0.5f;
        sw[q] = __sinf(h); cw[q] = __cosf(h);
    }

    // ---- initial product state (8 f32x2 per lane) ----
    const float laneF =
        ((lane & 32) ? si[5]  : ci[5])  *
        ((lane & 16) ? si[6]  : ci[6])  *
        ((lane & 8)  ? si[7]  : ci[7])  *
        ((lane & 4)  ? si[8]  : ci[8])  *
        ((lane & 2)  ? si[9]  : ci[9])  *
        ((lane & 1)  ? si[10] : ci[10]);
    const float B0 = (b ? si[0] : ci[0]) * laneF;

    f32x2 v2[8];
#pragma unroll
    for (int k = 0; k < 8; ++k) {
        const float base = B0 * ((k & 4) ? si[1] : ci[1])
                              * ((k & 2) ? si[2] : ci[2])
                              * ((k & 1) ? si[3] : ci[3]);
        v2[k].x = base * ci[4];
        v2[k].y = base * si[4];
    }

    // ---- folded coefficient constants ----
    const int l0 = lane & 1;
    // RY0 (wave bit) exchange coefs (verified r2):
    //   n_b = CC*own + PP*partner; layer0 sigma=+1; layers>=1 fold CZ(10,0)
    const float CC0 = cw[0];
    const float PP0 = b ? sw[0] : -sw[0];
    const float CCm = b ? (l0 ? -cw[0] : cw[0]) : cw[0];
    const float PPm = b ? sw[0] : (l0 ? sw[0] : -sw[0]);
    // RY1 (k bit2), fold CZ(0,1): sigma = -1 iff b (verified r2)
    const float S1n = b ? sw[1] : -sw[1];
    const float C1n = b ? -cw[1] : cw[1];
    // RY4 (comp), fold CZ(3,4): sigma1 = -1 iff k odd (verified r6)
    f32x2 C4p; C4p.x = cw[4];  C4p.y =  cw[4];
    f32x2 S4p; S4p.x = -sw[4]; S4p.y =  sw[4];
    f32x2 C4m; C4m.x = cw[4];  C4m.y = -cw[4];
    f32x2 S4m; S4m.x = sw[4];  S4m.y =  sw[4];
    // RY5 (lane bit5), fold CZ(4,5) (comp & lane5) — partner-fetch frame (r9)
    const bool hi5 = (lane & 32) != 0;
    const float SS5 = hi5 ?  sw[5] : -sw[5];
    const float C5m = hi5 ? -cw[5] :  cw[5];
    f32x2 Cv5; Cv5.x = cw[5]; Cv5.y = C5m;
    f32x2 Sv5; Sv5.x = SS5;   Sv5.y = sw[5];
    // lane-lane folds: own=(both)? -C:C ; cross=(either)? +S:-S (r3/r5/r6)
    const f32x2 C6v  = b2(((lane & 48) == 48) ? -cw[6]  : cw[6]);
    const f32x2 S6v  = b2((lane & 48) ? sw[6]  : -sw[6]);
    const f32x2 C7v  = b2(((lane & 24) == 24) ? -cw[7]  : cw[7]);
    const f32x2 S7v  = b2((lane & 24) ? sw[7]  : -sw[7]);
    const f32x2 C8v  = b2(((lane & 12) == 12) ? -cw[8]  : cw[8]);
    const f32x2 S8v  = b2((lane & 12) ? sw[8]  : -sw[8]);
    const f32x2 C9v  = b2(((lane & 6)  == 6)  ? -cw[9]  : cw[9]);
    const f32x2 S9v  = b2((lane & 6)  ? sw[9]  : -sw[9]);
    const f32x2 C10v = b2(((lane & 3)  == 3)  ? -cw[10] : cw[10]);
    const f32x2 S10v = b2((lane & 3)  ? sw[10] : -sw[10]);

    auto shfl32 = [](float t) { return __shfl_xor(t, 32); };
    auto shfl16 = [](float t) { return __shfl_xor(t, 16); };
    auto dppx8  = [](float t) { return dpp_mov<DPP_XOR8>(t); };
    auto dppx4  = [](float t) { return dpp_mov<DPP_XOR3>(dpp_mov<DPP_XOR7>(t)); };
    auto dppx2  = [](float t) { return dpp_mov<DPP_XOR2>(t); };
    auto dppx1  = [](float t) { return dpp_mov<DPP_XOR1>(t); };

    auto layer = [&](int l, float CC, float PP) {
        // ---- RY0 on wave bit: LDS exchange, double-buffered, 1 barrier ----
#pragma unroll
        for (int k = 0; k < 8; ++k) buf[l & 1][wid][k][lane] = v2[k];
        __syncthreads();
        f32x2 pr[8];
#pragma unroll
        for (int k = 0; k < 8; ++k) pr[k] = buf[l & 1][wid ^ 1][k][lane];
        const f32x2 ccv = b2(CC), ppv = b2(PP);
#pragma unroll
        for (int k = 0; k < 8; ++k) v2[k] = fma2(ccv, v2[k], ppv * pr[k]);

        // ---- RY1 (k bit2), fold CZ(0,1) via wave-uniform sigma ----
        {
            const f32x2 c1 = b2(cw[1]), s1 = b2(sw[1]);
            const f32x2 s1n = b2(S1n), c1n = b2(C1n);
#pragma unroll
            for (int g = 0; g < 4; ++g) {
                const f32x2 a_ = v2[g], bb_ = v2[g | 4];
                v2[g]     = fma2(c1, a_, s1n * bb_);
                v2[g | 4] = fma2(s1, a_, c1n * bb_);
            }
        }
        RY_K_F8(1, 4, cw[2], sw[2])     // RY2 (k bit1), fold CZ(1,2) (k bit2)
        RY_K_F8(0, 2, cw[3], sw[3])     // RY3 (k bit0), fold CZ(2,3) (k bit1)

        // ---- RY4 (comp), fold CZ(3,4) (k bit0) ----
#pragma unroll
        for (int k = 0; k < 8; ++k) {
            const f32x2 s_ = __builtin_shufflevector(v2[k], v2[k], 1, 0);
            v2[k] = (k & 1) ? fma2(C4m, v2[k], S4m * s_)
                            : fma2(C4p, v2[k], S4p * s_);
        }

        RY_DS_B8(shfl32, Cv5, Sv5)      // RY5,  fold CZ(4,5)  — DS batched
        RY_DS_B8(shfl16, C6v, S6v)      // RY6,  fold CZ(5,6)  — DS batched
        RY_DPP8(dppx8,  C7v,  S7v)      // RY7,  fold CZ(6,7)  — DPP
        RY_DPP8(dppx4,  C8v,  S8v)      // RY8,  fold CZ(7,8)  — DPP x2
        RY_DPP8(dppx2,  C9v,  S9v)      // RY9,  fold CZ(8,9)  — DPP
        RY_DPP8(dppx1,  C10v, S10v)     // RY10, fold CZ(9,10) — DPP
        // CZ(10,0) -> folded into next layer's RY0 (CCm/PPm); pure sign
        // after the last layer (probs = amp^2).
    };

    layer(0, CC0, PP0);
#pragma unroll 1
    for (int l = 1; l < 6; ++l) layer(l, CCm, PPm);

    // ---- measurement: out[w] = sum_i amp_i^2 * (1 - 2*bit_w(i)) ----
    f32x2 T = b2(0.f), A2 = b2(0.f), A1 = b2(0.f), A0 = b2(0.f);
#pragma unroll
    for (int k = 0; k < 8; ++k) {
        const f32x2 p = v2[k] * v2[k];
        T = T + p;
        if (k & 4) A2 = A2 + p;
        if (k & 2) A1 = A1 + p;
        if (k & 1) A0 = A0 + p;
    }
    const float tot = T.x + T.y;

    float q[NQ];
    q[0] = b ? -tot : tot;              // wire 0 (wave bit)
    q[1] = tot - 2.f * (A2.x + A2.y);   // wire 1 (k bit2)
    q[2] = tot - 2.f * (A1.x + A1.y);   // wire 2 (k bit1)
    q[3] = tot - 2.f * (A0.x + A0.y);   // wire 3 (k bit0)
    q[4] = tot - 2.f * T.y;             // wire 4 (comp)
    q[5]  = (lane & 32) ? -tot : tot;   // wires 5..10 (lane bits 5..0)
    q[6]  = (lane & 16) ? -tot : tot;
    q[7]  = (lane & 8)  ? -tot : tot;
    q[8]  = (lane & 4)  ? -tot : tot;
    q[9]  = (lane & 2)  ? -tot : tot;
    q[10] = (lane & 1)  ? -tot : tot;

    // per-wave reduction (verified r9 stage-major form)
#pragma unroll
    for (int wq = 0; wq < NQ; ++wq) q[wq] += __shfl_xor(q[wq], 32);
#pragma unroll
    for (int wq = 0; wq < NQ; ++wq) q[wq] += __shfl_xor(q[wq], 16);
#pragma unroll
    for (int wq = 0; wq < NQ; ++wq) q[wq] += dpp_mov<DPP_XOR8>(q[wq]);
#pragma unroll
    for (int wq = 0; wq < NQ; ++wq)
        q[wq] += dpp_mov<DPP_XOR3>(dpp_mov<DPP_XOR7>(q[wq]));
#pragma unroll
    for (int wq = 0; wq < NQ; ++wq) q[wq] += dpp_mov<DPP_XOR2>(q[wq]);
#pragma unroll
    for (int wq = 0; wq < NQ; ++wq) q[wq] += dpp_mov<DPP_XOR1>(q[wq]);

    if (lane == 0) {
#pragma unroll
        for (int wq = 0; wq < NQ; ++wq) qbuf[wid][wq] = q[wq];
    }
    __syncthreads();
    if (b == 0 && lane < NQ) {
        out[n * NQ + lane] = qbuf[wid][lane] + qbuf[wid + 1][lane];
    }
}

extern "C" void kernel_launch(void* const* d_in, const int* in_sizes, int n_in,
                              void* d_out, int out_size, void* d_ws, size_t ws_size,
                              hipStream_t stream) {
    const float* x = (const float*)d_in[0];   // [8,256,16] f32
    const float* w = (const float*)d_in[1];   // [11] f32
    float* out = (float*)d_out;               // [8,256,11] f32

    // 2048 samples, 2 waves each, 4 waves (2 samples) per block -> 1024 blocks
    qru_kernel<<<1024, 256, 0, stream>>>(x, w, out);
}